// Round 9
// baseline (727.059 us; speedup 1.0000x reference)
//
#include <hip/hip_runtime.h>
#include <hip/hip_bf16.h>
#include <math.h>

#define N_NODES 65536
#define N_EDGES 524288
#define IN_CH 128
#define HC 64
#define N_GRAPHS 512
#define BUCKET_CAP 64

// ---------------------------------------------------------------------------
// Build per-destination edge buckets. Each entry packs (eid, src) so the
// aggregate kernel needs no second dependent index lookup.
// With E/N = 8 (Poisson), P(deg > 64) ~ 1e-36 per node: cap 64 is safe.
// ---------------------------------------------------------------------------
__global__ void build_buckets(const int* __restrict__ ei, int* __restrict__ cnt,
                              int2* __restrict__ bucket) {
    int e = blockIdx.x * 256 + threadIdx.x;
    if (e >= N_EDGES) return;
    int s = ei[e];                        // src row (coalesced)
    int d = ei[N_EDGES + e];              // dst row (coalesced)
    int pos = atomicAdd(&cnt[d], 1);
    if (pos < BUCKET_CAP) bucket[d * BUCKET_CAP + pos] = make_int2(e, s);
}

// ---------------------------------------------------------------------------
// Fused node GEMM, scalar-weight layout: lane = node (64 nodes/block),
// wave = 16-channel group; each thread accumulates 16 channels x 4 matrices.
// Weight reads are wave-uniform -> scalar loads (s_load_dwordx16) on the
// scalar pipe; x comes from LDS (one ds_read_b32 per kk, per-lane). Issue
// mix per kk: 64 v_fmac + 1 ds_read + 4 s_loads => ~90% FMA occupancy of
// the VALU, weight traffic entirely off the vector-memory path.
// LDS rows padded by 4 floats: float4-aligned staging, 8-way read conflict
// (~17 cy) vs 128 cy FMA per kk — negligible.
// ---------------------------------------------------------------------------
template <int FIN>
__global__ __launch_bounds__(256) void node_gemm(
    const float* __restrict__ xin,
    const float* __restrict__ Wq, const float* __restrict__ Wk,
    const float* __restrict__ Wv, const float* __restrict__ Ws,
    const float* __restrict__ bq, const float* __restrict__ bk,
    const float* __restrict__ bv, const float* __restrict__ bs,
    float* __restrict__ q, float* __restrict__ kv,
    float* __restrict__ hout) {
    constexpr int NPB = 64;               // nodes per block (= lanes)
    constexpr int PAD = 4;                // keeps staging float4-aligned
    constexpr int STRIDE = FIN + PAD;
    __shared__ float xs[NPB * STRIDE];
    const int lane = threadIdx.x & 63;    // node within block
    const int wid = threadIdx.x >> 6;     // channel group 0..3
    const int ch0 = wid * 16;
    const int n0 = blockIdx.x * NPB;

    // coalesced float4 staging into padded rows
    {
        const float4* xin4 = (const float4*)(xin + (size_t)n0 * FIN);
        for (int idx = threadIdx.x; idx < NPB * FIN / 4; idx += 256) {
            int nrow = idx / (FIN / 4);
            int c4 = idx % (FIN / 4);
            *(float4*)&xs[nrow * STRIDE + c4 * 4] = xin4[idx];
        }
    }

    float accq[16], acck[16], accv[16], accs[16];
#pragma unroll
    for (int j = 0; j < 16; ++j) {        // bias folded into acc init (s_load)
        accq[j] = bq[ch0 + j];
        acck[j] = bk[ch0 + j];
        accv[j] = bv[ch0 + j];
        accs[j] = bs[ch0 + j];
    }
    __syncthreads();

    const float* xrow = &xs[lane * STRIDE];
#pragma unroll 2
    for (int kk = 0; kk < FIN; ++kk) {
        float xv = xrow[kk];
        const float* wqr = Wq + kk * HC + ch0;   // wave-uniform bases
        const float* wkr = Wk + kk * HC + ch0;
        const float* wvr = Wv + kk * HC + ch0;
        const float* wsr = Ws + kk * HC + ch0;
#pragma unroll
        for (int j = 0; j < 16; ++j) {
            accq[j] = fmaf(xv, wqr[j], accq[j]);
            acck[j] = fmaf(xv, wkr[j], acck[j]);
            accv[j] = fmaf(xv, wvr[j], accv[j]);
            accs[j] = fmaf(xv, wsr[j], accs[j]);
        }
    }

    const int n = n0 + lane;
#pragma unroll
    for (int j4 = 0; j4 < 4; ++j4) {
        *(float4*)&q[(size_t)n * HC + ch0 + j4 * 4] =
            make_float4(accq[j4*4], accq[j4*4+1], accq[j4*4+2], accq[j4*4+3]);
        *(float4*)&kv[(size_t)n * 128 + ch0 + j4 * 4] =
            make_float4(acck[j4*4], acck[j4*4+1], acck[j4*4+2], acck[j4*4+3]);
        *(float4*)&kv[(size_t)n * 128 + 64 + ch0 + j4 * 4] =
            make_float4(accv[j4*4], accv[j4*4+1], accv[j4*4+2], accv[j4*4+3]);
        *(float4*)&hout[(size_t)n * HC + ch0 + j4 * 4] =
            make_float4(accs[j4*4], accs[j4*4+1], accs[j4*4+2], accs[j4*4+3]);
    }
}

// ---------------------------------------------------------------------------
// Per-destination-node aggregation with in-register online softmax.
// One wave (64 lanes) per node; lane = channel; head = lane>>4.
// (eid,src) pairs prefetched lane-parallel in ONE 8B load (lane j holds
// edge j); per-iteration broadcast via readlane (SGPR, saddr-form gathers).
// Edges are processed PAIRWISE: one rescale per pair, two independent
// shuffle-reduce chains (2x ILP), 3 exps/pair instead of 4 — exact
// online-softmax algebra, halved serial chain. 1-pair-ahead prefetch
// overlaps gather latency with the compute chain.
// ---------------------------------------------------------------------------
template <int RELU>
__global__ __launch_bounds__(256) void aggregate(
    const float* __restrict__ q, const float* __restrict__ kv,
    const float* __restrict__ ea,
    const float* __restrict__ We, const float* __restrict__ be,
    const int* __restrict__ cnt,
    const int2* __restrict__ bucket, float* __restrict__ hout) {
    const int wave = threadIdx.x >> 6;
    const int c = threadIdx.x & 63;
    const int n = blockIdx.x * 4 + wave;

    const float qc = q[n * HC + c] * 0.25f;   // fold 1/sqrt(16) into q
    int deg = cnt[n];
    if (deg > BUCKET_CAP) deg = BUCKET_CAP;

    // lane-parallel prefetch of (eid, src) pairs — single 8B load
    int myeid = 0, mysrc = 0;
    if (c < deg) {
        int2 b = bucket[n * BUCKET_CAP + c];
        myeid = b.x;
        mysrc = b.y;
    }

    const float bec = be[c];
    float wec[8];
#pragma unroll
    for (int f = 0; f < 8; ++f) wec[f] = We[f * HC + c];

    float m = -INFINITY, d = 0.f, o = 0.f;

    // edge-slot registers: current pair (A,B) and prefetch pair (nA,nB)
    float4 eA0, eA1, eB0, eB1, nA0, nA1, nB0, nB1;
    float kA, vA, kB, vB, nkA, nvA, nkB, nvB;

#define LOAD_EDGE(idx, E0, E1, KC, VC)                                   \
    {                                                                    \
        int eid_ = __builtin_amdgcn_readlane(myeid, (idx));              \
        int s_   = __builtin_amdgcn_readlane(mysrc, (idx));              \
        E0 = *(const float4*)(ea + (size_t)eid_ * 8);                    \
        E1 = *(const float4*)(ea + (size_t)eid_ * 8 + 4);                \
        KC = kv[(size_t)s_ * 128 + c];                                   \
        VC = kv[(size_t)s_ * 128 + 64 + c];                              \
    }

#define EDGE_PROJ(E0, E1, EC)                                            \
    float EC = bec;                                                      \
    EC = fmaf(E0.x, wec[0], EC); EC = fmaf(E0.y, wec[1], EC);            \
    EC = fmaf(E0.z, wec[2], EC); EC = fmaf(E0.w, wec[3], EC);            \
    EC = fmaf(E1.x, wec[4], EC); EC = fmaf(E1.y, wec[5], EC);            \
    EC = fmaf(E1.z, wec[6], EC); EC = fmaf(E1.w, wec[7], EC);

#define HEAD_REDUCE(P)                                                   \
    P += __shfl_xor(P, 1);  P += __shfl_xor(P, 2);                       \
    P += __shfl_xor(P, 4);  P += __shfl_xor(P, 8);

    const int npairs = deg >> 1;

    // initial fill of the current pair slots
    if (deg >= 2) {
        LOAD_EDGE(0, eA0, eA1, kA, vA);
        LOAD_EDGE(1, eB0, eB1, kB, vB);
    } else if (deg == 1) {
        LOAD_EDGE(0, eA0, eA1, kA, vA);
    }

    for (int p = 0; p < npairs; ++p) {
        // prefetch next pair (or odd tail) while computing current pair
        int base = (p + 1) * 2;
        if (base + 1 < deg) {
            LOAD_EDGE(base, nA0, nA1, nkA, nvA);
            LOAD_EDGE(base + 1, nB0, nB1, nkB, nvB);
        } else if (base < deg) {
            LOAD_EDGE(base, nA0, nA1, nkA, nvA);
        }

        EDGE_PROJ(eA0, eA1, ecA);
        EDGE_PROJ(eB0, eB1, ecB);

        float pA = qc * (kA + ecA);
        float pB = qc * (kB + ecB);
        HEAD_REDUCE(pA);
        HEAD_REDUCE(pB);

        float newm = fmaxf(m, fmaxf(pA, pB));
        float scale = __expf(m - newm);       // exp(-inf)=0 on first pair
        float wA = __expf(pA - newm);
        float wB = __expf(pB - newm);
        d = d * scale + wA + wB;
        o = o * scale + (vA + ecA) * wA + (vB + ecB) * wB;
        m = newm;

        // rotate prefetched slots into current
        eA0 = nA0; eA1 = nA1; kA = nkA; vA = nvA;
        eB0 = nB0; eB1 = nB1; kB = nkB; vB = nvB;
    }

    if (deg & 1) {                            // odd tail edge (in A slot)
        EDGE_PROJ(eA0, eA1, ecA);
        float pA = qc * (kA + ecA);
        HEAD_REDUCE(pA);
        float newm = fmaxf(m, pA);
        float scale = __expf(m - newm);
        float wA = __expf(pA - newm);
        d = d * scale + wA;
        o = o * scale + (vA + ecA) * wA;
    }

#undef LOAD_EDGE
#undef EDGE_PROJ
#undef HEAD_REDUCE

    float msg = (deg > 0) ? (o / d) : 0.f;    // d >= 1 whenever deg > 0
    float val = hout[n * HC + c] + msg;
    if (RELU) val = fmaxf(val, 0.f);
    hout[n * HC + c] = val;
}

// ---------------------------------------------------------------------------
// Mean pool. batch is sorted, so each graph's node range is found by binary
// search; one wave per graph, coalesced row sums with 4-way ILP. No atomics,
// no scratch, no finalize pass.
// ---------------------------------------------------------------------------
__device__ __forceinline__ int lower_bound(const int* __restrict__ b, int val) {
    int lo = 0, hi = N_NODES;
    while (lo < hi) {
        int mid = (lo + hi) >> 1;
        if (b[mid] < val) lo = mid + 1; else hi = mid;
    }
    return lo;
}

__global__ __launch_bounds__(256) void pool_graph(const float* __restrict__ h,
                                                  const int* __restrict__ batch,
                                                  float* __restrict__ out) {
    const int g = blockIdx.x * 4 + (threadIdx.x >> 6);
    const int c = threadIdx.x & 63;
    const int s = lower_bound(batch, g);
    const int e = lower_bound(batch, g + 1);

    float a0 = 0.f, a1 = 0.f, a2 = 0.f, a3 = 0.f;
    int i = s;
    for (; i + 4 <= e; i += 4) {
        a0 += h[(size_t)i * HC + c];
        a1 += h[(size_t)(i + 1) * HC + c];
        a2 += h[(size_t)(i + 2) * HC + c];
        a3 += h[(size_t)(i + 3) * HC + c];
    }
    for (; i < e; ++i) a0 += h[(size_t)i * HC + c];
    float acc = (a0 + a1) + (a2 + a3);
    out[g * HC + c] = acc / fmaxf((float)(e - s), 1.f);
}

// ---------------------------------------------------------------------------
extern "C" void kernel_launch(void* const* d_in, const int* in_sizes, int n_in,
                              void* d_out, int out_size, void* d_ws, size_t ws_size,
                              hipStream_t stream) {
    const float* x     = (const float*)d_in[0];
    const float* ea    = (const float*)d_in[1];
    const int*   ei    = (const int*)d_in[2];
    const int*   batch = (const int*)d_in[3];
    const float* Wq1 = (const float*)d_in[4];
    const float* Wk1 = (const float*)d_in[5];
    const float* Wv1 = (const float*)d_in[6];
    const float* We1 = (const float*)d_in[7];
    const float* Ws1 = (const float*)d_in[8];
    const float* Wq2 = (const float*)d_in[9];
    const float* Wk2 = (const float*)d_in[10];
    const float* Wv2 = (const float*)d_in[11];
    const float* We2 = (const float*)d_in[12];
    const float* Ws2 = (const float*)d_in[13];
    const float* bq1 = (const float*)d_in[14];
    const float* bk1 = (const float*)d_in[15];
    const float* bv1 = (const float*)d_in[16];
    const float* be1 = (const float*)d_in[17];
    const float* bs1 = (const float*)d_in[18];
    const float* bq2 = (const float*)d_in[19];
    const float* bk2 = (const float*)d_in[20];
    const float* bv2 = (const float*)d_in[21];
    const float* be2 = (const float*)d_in[22];
    const float* bs2 = (const float*)d_in[23];
    float* out = (float*)d_out;

    char* ws = (char*)d_ws;
    size_t off = 0;
    auto alloc = [&](size_t bytes) -> void* {
        void* p = ws + off;
        off += (bytes + 255) & ~(size_t)255;
        return p;
    };
    int*   cnt    = (int*)alloc((size_t)N_NODES * 4);
    int2*  bucket = (int2*)alloc((size_t)N_NODES * BUCKET_CAP * 8);
    float* q      = (float*)alloc((size_t)N_NODES * HC * 4);
    float* kv     = (float*)alloc((size_t)N_NODES * 128 * 4);
    float* h1     = (float*)alloc((size_t)N_NODES * HC * 4);
    float* h2     = (float*)alloc((size_t)N_NODES * HC * 4);

    hipMemsetAsync(cnt, 0, (size_t)N_NODES * 4, stream);
    build_buckets<<<N_EDGES / 256, 256, 0, stream>>>(ei, cnt, bucket);

    // ---- layer 1 ----
    node_gemm<IN_CH><<<N_NODES / 64, 256, 0, stream>>>(
        x, Wq1, Wk1, Wv1, Ws1, bq1, bk1, bv1, bs1, q, kv, h1);
    aggregate<1><<<N_NODES / 4, 256, 0, stream>>>(
        q, kv, ea, We1, be1, cnt, bucket, h1);

    // ---- layer 2 ----
    node_gemm<HC><<<N_NODES / 64, 256, 0, stream>>>(
        h1, Wq2, Wk2, Wv2, Ws2, bq2, bk2, bv2, bs2, q, kv, h2);
    aggregate<0><<<N_NODES / 4, 256, 0, stream>>>(
        q, kv, ea, We2, be2, cnt, bucket, h2);

    // ---- mean pool ----
    pool_graph<<<N_GRAPHS / 4, 256, 0, stream>>>(h2, batch, out);
}

// Round 10
// 382.131 us; speedup vs baseline: 1.9026x; 1.9026x over previous
//
#include <hip/hip_runtime.h>
#include <hip/hip_bf16.h>
#include <math.h>

#define N_NODES 65536
#define N_EDGES 524288
#define IN_CH 128
#define HC 64
#define N_GRAPHS 512
#define BUCKET_CAP 64

// ---------------------------------------------------------------------------
// Build per-destination edge buckets. Each entry packs (eid, src) so the
// aggregate kernel needs no second dependent index lookup.
// ---------------------------------------------------------------------------
__global__ void build_buckets(const int* __restrict__ ei, int* __restrict__ cnt,
                              int2* __restrict__ bucket) {
    int e = blockIdx.x * 256 + threadIdx.x;
    if (e >= N_EDGES) return;
    int s = ei[e];                        // src row (coalesced)
    int d = ei[N_EDGES + e];              // dst row (coalesced)
    int pos = atomicAdd(&cnt[d], 1);
    if (pos < BUCKET_CAP) bucket[d * BUCKET_CAP + pos] = make_int2(e, s);
}

// ---------------------------------------------------------------------------
// Fused node GEMM (r8 structure, halved block): 128 threads = 2 waves,
// 32 nodes/block, 16 nodes/thread. lane = channel, wave = 16-node group.
// 16 KB LDS (vs 32) and ~110 VGPR -> ~4 waves/SIMD resident (r8 had 2,
// occupancy 19%, VALUBusy 55%: stalls exposed at chunk boundaries).
// Weights double-buffered in named A/B register sets; bias in acc init.
// ---------------------------------------------------------------------------
#define NG_PREFETCH(CHUNK, WQ, WK, WV, WS)                                \
    _Pragma("unroll")                                                     \
    for (int u = 0; u < 4; ++u) {                                         \
        WQ[u] = Wq[((CHUNK) * 4 + u) * HC + c];                           \
        WK[u] = Wk[((CHUNK) * 4 + u) * HC + c];                           \
        WV[u] = Wv[((CHUNK) * 4 + u) * HC + c];                           \
        WS[u] = Ws[((CHUNK) * 4 + u) * HC + c];                           \
    }

#define NG_COMPUTE(CHUNK, WQ, WK, WV, WS)                                 \
    _Pragma("unroll")                                                     \
    for (int t = 0; t < NPT; ++t) {                                       \
        float4 xv = *(const float4*)&xs[(wid * NPT + t) * FIN + (CHUNK) * 4]; \
        aq[t] = fmaf(xv.x, WQ[0], aq[t]);                                 \
        aq[t] = fmaf(xv.y, WQ[1], aq[t]);                                 \
        aq[t] = fmaf(xv.z, WQ[2], aq[t]);                                 \
        aq[t] = fmaf(xv.w, WQ[3], aq[t]);                                 \
        ak[t] = fmaf(xv.x, WK[0], ak[t]);                                 \
        ak[t] = fmaf(xv.y, WK[1], ak[t]);                                 \
        ak[t] = fmaf(xv.z, WK[2], ak[t]);                                 \
        ak[t] = fmaf(xv.w, WK[3], ak[t]);                                 \
        av[t] = fmaf(xv.x, WV[0], av[t]);                                 \
        av[t] = fmaf(xv.y, WV[1], av[t]);                                 \
        av[t] = fmaf(xv.z, WV[2], av[t]);                                 \
        av[t] = fmaf(xv.w, WV[3], av[t]);                                 \
        as_[t] = fmaf(xv.x, WS[0], as_[t]);                               \
        as_[t] = fmaf(xv.y, WS[1], as_[t]);                               \
        as_[t] = fmaf(xv.z, WS[2], as_[t]);                               \
        as_[t] = fmaf(xv.w, WS[3], as_[t]);                               \
    }

template <int FIN>
__global__ __launch_bounds__(128) void node_gemm(
    const float* __restrict__ xin,
    const float* __restrict__ Wq, const float* __restrict__ Wk,
    const float* __restrict__ Wv, const float* __restrict__ Ws,
    const float* __restrict__ bq, const float* __restrict__ bk,
    const float* __restrict__ bv, const float* __restrict__ bs,
    float* __restrict__ q, float* __restrict__ kv,
    float* __restrict__ hout) {
    constexpr int NPB = 32;               // nodes per block
    constexpr int NPT = 16;               // nodes per thread
    constexpr int NCH = FIN / 4;          // 4-wide K chunks
    __shared__ float xs[NPB * FIN];
    const int c = threadIdx.x & 63;       // channel = lane
    const int wid = threadIdx.x >> 6;     // wave -> nodes [wid*16, wid*16+16)
    const int n0 = blockIdx.x * NPB;

    float wAq[4], wAk[4], wAv[4], wAs[4];
    float wBq[4], wBk[4], wBv[4], wBs[4];

    // chunk-0 weight prefetch issues before (and overlaps) LDS staging
    NG_PREFETCH(0, wAq, wAk, wAv, wAs)

    const float4* xin4 = (const float4*)(xin + (size_t)n0 * FIN);
    float4* xs4 = (float4*)xs;
    for (int i = threadIdx.x; i < NPB * FIN / 4; i += 128)
        xs4[i] = xin4[i];

    float aq[NPT], ak[NPT], av[NPT], as_[NPT];
    const float biasq = bq[c], biask = bk[c], biasv = bv[c], biass = bs[c];
#pragma unroll
    for (int t = 0; t < NPT; ++t) {
        aq[t] = biasq; ak[t] = biask; av[t] = biasv; as_[t] = biass;
    }
    __syncthreads();

    for (int kc = 0; kc < NCH; kc += 2) {
        NG_PREFETCH(kc + 1, wBq, wBk, wBv, wBs)
        NG_COMPUTE(kc, wAq, wAk, wAv, wAs)
        if (kc + 2 < NCH) {
            NG_PREFETCH(kc + 2, wAq, wAk, wAv, wAs)
        }
        NG_COMPUTE(kc + 1, wBq, wBk, wBv, wBs)
    }

#pragma unroll
    for (int t = 0; t < NPT; ++t) {
        int n = n0 + wid * NPT + t;
        q[n * HC + c] = aq[t];
        kv[(size_t)n * 128 + c] = ak[t];
        kv[(size_t)n * 128 + 64 + c] = av[t];
        hout[n * HC + c] = as_[t];
    }
}

#undef NG_PREFETCH
#undef NG_COMPUTE

// ---------------------------------------------------------------------------
// DPP-based 16-lane sum (broadcast to all 16 lanes of each row group).
// Steps: quad pair-swap (0xB1), quad 2-swap (0x4E), row_half_mirror (0x141),
// row_mirror (0x140). Each is a VALU op (~2cy) vs ds_swizzle (~30cy) for
// __shfl_xor: the serial reduce chain drops from ~100cy to ~10cy.
// Equivalent to shfl_xor{1,2,4,8} by the equal-within-group invariant.
// ---------------------------------------------------------------------------
__device__ __forceinline__ float dpp_sum16(float x) {
    int t;
    t = __builtin_amdgcn_update_dpp(0, __float_as_int(x), 0xB1, 0xF, 0xF, true);
    x += __int_as_float(t);
    t = __builtin_amdgcn_update_dpp(0, __float_as_int(x), 0x4E, 0xF, 0xF, true);
    x += __int_as_float(t);
    t = __builtin_amdgcn_update_dpp(0, __float_as_int(x), 0x141, 0xF, 0xF, true);
    x += __int_as_float(t);
    t = __builtin_amdgcn_update_dpp(0, __float_as_int(x), 0x140, 0xF, 0xF, true);
    x += __int_as_float(t);
    return x;
}

// ---------------------------------------------------------------------------
// Per-destination-node aggregation with in-register online softmax.
// One wave (64 lanes) per node; lane = channel; head = lane>>4.
// (eid,src) pairs prefetched lane-parallel; readlane broadcast; pairwise
// online softmax (one rescale per pair, 3 exps); 1-pair-ahead prefetch;
// head reduce via DPP (VALU) instead of shfl (LDS pipe).
// ---------------------------------------------------------------------------
template <int RELU>
__global__ __launch_bounds__(256) void aggregate(
    const float* __restrict__ q, const float* __restrict__ kv,
    const float* __restrict__ ea,
    const float* __restrict__ We, const float* __restrict__ be,
    const int* __restrict__ cnt,
    const int2* __restrict__ bucket, float* __restrict__ hout) {
    const int wave = threadIdx.x >> 6;
    const int c = threadIdx.x & 63;
    const int n = blockIdx.x * 4 + wave;

    const float qc = q[n * HC + c] * 0.25f;   // fold 1/sqrt(16) into q
    int deg = cnt[n];
    if (deg > BUCKET_CAP) deg = BUCKET_CAP;

    // lane-parallel prefetch of (eid, src) pairs — single 8B load
    int myeid = 0, mysrc = 0;
    if (c < deg) {
        int2 b = bucket[n * BUCKET_CAP + c];
        myeid = b.x;
        mysrc = b.y;
    }

    const float bec = be[c];
    float wec[8];
#pragma unroll
    for (int f = 0; f < 8; ++f) wec[f] = We[f * HC + c];

    float m = -INFINITY, d = 0.f, o = 0.f;

    // edge-slot registers: current pair (A,B) and prefetch pair (nA,nB)
    float4 eA0, eA1, eB0, eB1, nA0, nA1, nB0, nB1;
    float kA, vA, kB, vB, nkA, nvA, nkB, nvB;

#define LOAD_EDGE(idx, E0, E1, KC, VC)                                   \
    {                                                                    \
        int eid_ = __builtin_amdgcn_readlane(myeid, (idx));              \
        int s_   = __builtin_amdgcn_readlane(mysrc, (idx));              \
        E0 = *(const float4*)(ea + (size_t)eid_ * 8);                    \
        E1 = *(const float4*)(ea + (size_t)eid_ * 8 + 4);                \
        KC = kv[(size_t)s_ * 128 + c];                                   \
        VC = kv[(size_t)s_ * 128 + 64 + c];                              \
    }

#define EDGE_PROJ(E0, E1, EC)                                            \
    float EC = bec;                                                      \
    EC = fmaf(E0.x, wec[0], EC); EC = fmaf(E0.y, wec[1], EC);            \
    EC = fmaf(E0.z, wec[2], EC); EC = fmaf(E0.w, wec[3], EC);            \
    EC = fmaf(E1.x, wec[4], EC); EC = fmaf(E1.y, wec[5], EC);            \
    EC = fmaf(E1.z, wec[6], EC); EC = fmaf(E1.w, wec[7], EC);

    const int npairs = deg >> 1;

    // initial fill of the current pair slots
    if (deg >= 2) {
        LOAD_EDGE(0, eA0, eA1, kA, vA);
        LOAD_EDGE(1, eB0, eB1, kB, vB);
    } else if (deg == 1) {
        LOAD_EDGE(0, eA0, eA1, kA, vA);
    }

    for (int p = 0; p < npairs; ++p) {
        // prefetch next pair (or odd tail) while computing current pair
        int base = (p + 1) * 2;
        if (base + 1 < deg) {
            LOAD_EDGE(base, nA0, nA1, nkA, nvA);
            LOAD_EDGE(base + 1, nB0, nB1, nkB, nvB);
        } else if (base < deg) {
            LOAD_EDGE(base, nA0, nA1, nkA, nvA);
        }

        EDGE_PROJ(eA0, eA1, ecA);
        EDGE_PROJ(eB0, eB1, ecB);

        float pA = dpp_sum16(qc * (kA + ecA));
        float pB = dpp_sum16(qc * (kB + ecB));

        float newm = fmaxf(m, fmaxf(pA, pB));
        float scale = __expf(m - newm);       // exp(-inf)=0 on first pair
        float wA = __expf(pA - newm);
        float wB = __expf(pB - newm);
        d = d * scale + wA + wB;
        o = o * scale + (vA + ecA) * wA + (vB + ecB) * wB;
        m = newm;

        // rotate prefetched slots into current
        eA0 = nA0; eA1 = nA1; kA = nkA; vA = nvA;
        eB0 = nB0; eB1 = nB1; kB = nkB; vB = nvB;
    }

    if (deg & 1) {                            // odd tail edge (in A slot)
        EDGE_PROJ(eA0, eA1, ecA);
        float pA = dpp_sum16(qc * (kA + ecA));
        float newm = fmaxf(m, pA);
        float scale = __expf(m - newm);
        float wA = __expf(pA - newm);
        d = d * scale + wA;
        o = o * scale + (vA + ecA) * wA;
    }

#undef LOAD_EDGE
#undef EDGE_PROJ

    float msg = (deg > 0) ? (o / d) : 0.f;    // d >= 1 whenever deg > 0
    float val = hout[n * HC + c] + msg;
    if (RELU) val = fmaxf(val, 0.f);
    hout[n * HC + c] = val;
}

// ---------------------------------------------------------------------------
// Mean pool. batch is sorted, so each graph's node range is found by binary
// search; one wave per graph, coalesced row sums with 4-way ILP.
// ---------------------------------------------------------------------------
__device__ __forceinline__ int lower_bound(const int* __restrict__ b, int val) {
    int lo = 0, hi = N_NODES;
    while (lo < hi) {
        int mid = (lo + hi) >> 1;
        if (b[mid] < val) lo = mid + 1; else hi = mid;
    }
    return lo;
}

__global__ __launch_bounds__(256) void pool_graph(const float* __restrict__ h,
                                                  const int* __restrict__ batch,
                                                  float* __restrict__ out) {
    const int g = blockIdx.x * 4 + (threadIdx.x >> 6);
    const int c = threadIdx.x & 63;
    const int s = lower_bound(batch, g);
    const int e = lower_bound(batch, g + 1);

    float a0 = 0.f, a1 = 0.f, a2 = 0.f, a3 = 0.f;
    int i = s;
    for (; i + 4 <= e; i += 4) {
        a0 += h[(size_t)i * HC + c];
        a1 += h[(size_t)(i + 1) * HC + c];
        a2 += h[(size_t)(i + 2) * HC + c];
        a3 += h[(size_t)(i + 3) * HC + c];
    }
    for (; i < e; ++i) a0 += h[(size_t)i * HC + c];
    float acc = (a0 + a1) + (a2 + a3);
    out[g * HC + c] = acc / fmaxf((float)(e - s), 1.f);
}

// ---------------------------------------------------------------------------
extern "C" void kernel_launch(void* const* d_in, const int* in_sizes, int n_in,
                              void* d_out, int out_size, void* d_ws, size_t ws_size,
                              hipStream_t stream) {
    const float* x     = (const float*)d_in[0];
    const float* ea    = (const float*)d_in[1];
    const int*   ei    = (const int*)d_in[2];
    const int*   batch = (const int*)d_in[3];
    const float* Wq1 = (const float*)d_in[4];
    const float* Wk1 = (const float*)d_in[5];
    const float* Wv1 = (const float*)d_in[6];
    const float* We1 = (const float*)d_in[7];
    const float* Ws1 = (const float*)d_in[8];
    const float* Wq2 = (const float*)d_in[9];
    const float* Wk2 = (const float*)d_in[10];
    const float* Wv2 = (const float*)d_in[11];
    const float* We2 = (const float*)d_in[12];
    const float* Ws2 = (const float*)d_in[13];
    const float* bq1 = (const float*)d_in[14];
    const float* bk1 = (const float*)d_in[15];
    const float* bv1 = (const float*)d_in[16];
    const float* be1 = (const float*)d_in[17];
    const float* bs1 = (const float*)d_in[18];
    const float* bq2 = (const float*)d_in[19];
    const float* bk2 = (const float*)d_in[20];
    const float* bv2 = (const float*)d_in[21];
    const float* be2 = (const float*)d_in[22];
    const float* bs2 = (const float*)d_in[23];
    float* out = (float*)d_out;

    char* ws = (char*)d_ws;
    size_t off = 0;
    auto alloc = [&](size_t bytes) -> void* {
        void* p = ws + off;
        off += (bytes + 255) & ~(size_t)255;
        return p;
    };
    int*   cnt    = (int*)alloc((size_t)N_NODES * 4);
    int2*  bucket = (int2*)alloc((size_t)N_NODES * BUCKET_CAP * 8);
    float* q      = (float*)alloc((size_t)N_NODES * HC * 4);
    float* kv     = (float*)alloc((size_t)N_NODES * 128 * 4);
    float* h1     = (float*)alloc((size_t)N_NODES * HC * 4);
    float* h2     = (float*)alloc((size_t)N_NODES * HC * 4);

    hipMemsetAsync(cnt, 0, (size_t)N_NODES * 4, stream);
    build_buckets<<<N_EDGES / 256, 256, 0, stream>>>(ei, cnt, bucket);

    // ---- layer 1 ----
    node_gemm<IN_CH><<<N_NODES / 32, 128, 0, stream>>>(
        x, Wq1, Wk1, Wv1, Ws1, bq1, bk1, bv1, bs1, q, kv, h1);
    aggregate<1><<<N_NODES / 4, 256, 0, stream>>>(
        q, kv, ea, We1, be1, cnt, bucket, h1);

    // ---- layer 2 ----
    node_gemm<HC><<<N_NODES / 32, 128, 0, stream>>>(
        h1, Wq2, Wk2, Wv2, Ws2, bq2, bk2, bv2, bs2, q, kv, h2);
    aggregate<0><<<N_NODES / 4, 256, 0, stream>>>(
        q, kv, ea, We2, be2, cnt, bucket, h2);

    // ---- mean pool ----
    pool_graph<<<N_GRAPHS / 4, 256, 0, stream>>>(h2, batch, out);
}

// Round 11
// 325.770 us; speedup vs baseline: 2.2318x; 1.1730x over previous
//
#include <hip/hip_runtime.h>
#include <hip/hip_bf16.h>
#include <math.h>

#define N_NODES 65536
#define N_EDGES 524288
#define IN_CH 128
#define HC 64
#define N_GRAPHS 512
#define BUCKET_CAP 64

typedef __attribute__((ext_vector_type(8))) short short8v;
typedef __attribute__((ext_vector_type(4))) float float4v;

__device__ __forceinline__ ushort f32_to_bf16_rne(float x) {
    unsigned u = __float_as_uint(x);
    return (ushort)((u + 0x7fffu + ((u >> 16) & 1u)) >> 16);
}
__device__ __forceinline__ float bf16_to_f32(ushort h) {
    return __uint_as_float(((unsigned)h) << 16);
}

// ---------------------------------------------------------------------------
// Build per-destination edge buckets. Each entry packs (eid, src).
// ---------------------------------------------------------------------------
__global__ void build_buckets(const int* __restrict__ ei, int* __restrict__ cnt,
                              int2* __restrict__ bucket) {
    int e = blockIdx.x * 256 + threadIdx.x;
    if (e >= N_EDGES) return;
    int s = ei[e];
    int d = ei[N_EDGES + e];
    int pos = atomicAdd(&cnt[d], 1);
    if (pos < BUCKET_CAP) bucket[d * BUCKET_CAP + pos] = make_int2(e, s);
}

// ---------------------------------------------------------------------------
// Pack the 8 projection matrices into MFMA B-fragment order, split bf16
// hi/lo (Markidis). Fragment f=(ks*4+ct)*64+lane, element j:
//   W[ks*32 + (lane>>4)*8 + j][ct*16 + (lane&15)]
// Layer1 mats (FIN=128): 1024 frags each; layer2 (FIN=64): 512 each.
// ---------------------------------------------------------------------------
__global__ void pack_weights(
    const float* __restrict__ Wq1, const float* __restrict__ Wk1,
    const float* __restrict__ Wv1, const float* __restrict__ Ws1,
    const float* __restrict__ Wq2, const float* __restrict__ Wk2,
    const float* __restrict__ Wv2, const float* __restrict__ Ws2,
    ushort* __restrict__ wf1_hi, ushort* __restrict__ wf1_lo,
    ushort* __restrict__ wf2_hi, ushort* __restrict__ wf2_lo) {
    int f = blockIdx.x * 256 + threadIdx.x;
    if (f >= 6144) return;
    const float* W;
    ushort *ph, *pl;
    int fl;
    if (f < 4096) {
        int mat = f >> 10; fl = f & 1023;
        W = (mat == 0) ? Wq1 : (mat == 1) ? Wk1 : (mat == 2) ? Wv1 : Ws1;
        ph = wf1_hi + (size_t)mat * 1024 * 8;
        pl = wf1_lo + (size_t)mat * 1024 * 8;
    } else {
        int g = f - 4096;
        int mat = g >> 9; fl = g & 511;
        W = (mat == 0) ? Wq2 : (mat == 1) ? Wk2 : (mat == 2) ? Wv2 : Ws2;
        ph = wf2_hi + (size_t)mat * 512 * 8;
        pl = wf2_lo + (size_t)mat * 512 * 8;
    }
    int lane = fl & 63;
    int ct = (fl >> 6) & 3;
    int ks = fl >> 8;
    int col = ct * 16 + (lane & 15);
    int k0 = ks * 32 + (lane >> 4) * 8;
    ushort h8[8], l8[8];
#pragma unroll
    for (int j = 0; j < 8; ++j) {
        float w = W[(size_t)(k0 + j) * HC + col];
        ushort h = f32_to_bf16_rne(w);
        float r = w - bf16_to_f32(h);
        h8[j] = h;
        l8[j] = f32_to_bf16_rne(r);
    }
    *(uint4*)&ph[(size_t)fl * 8] = *(uint4*)h8;
    *(uint4*)&pl[(size_t)fl * 8] = *(uint4*)l8;
}

// ---------------------------------------------------------------------------
// MFMA node GEMM (split-bf16, 3 passes: hi*hi + hi*lo + lo*hi, f32 acc —
// ~2^-18 residual, f32-grade). 256 thr = 4 waves, 128 nodes/block; wave w
// owns 32 nodes = 2 M-tiles of 16. Outputs 4 matrices x 64ch = 16 N-tiles.
// x staged in LDS as bf16 hi/lo planes, 16B chunks XOR-swizzled
// (chunk ^ (row&7)) so A-fragment ds_read_b128 is bank-conflict-free.
// Per-wave B-fragment loads hit L2 (pre-swizzled by pack_weights).
// C layout (m89-verified): row=(lane>>4)*4+reg, col=lane&15.
// ---------------------------------------------------------------------------
template <int FIN>
__global__ __launch_bounds__(256, 2) void node_gemm_mfma(
    const float* __restrict__ xin,
    const ushort* __restrict__ wf_hi, const ushort* __restrict__ wf_lo,
    const float* __restrict__ bq, const float* __restrict__ bk,
    const float* __restrict__ bv, const float* __restrict__ bs,
    float* __restrict__ q, float* __restrict__ kv, float* __restrict__ hout) {
    constexpr int NPB = 128;              // nodes per block
    constexpr int KS = FIN / 32;          // MFMA K-steps
    constexpr int KC = FIN / 8;           // 16B chunks per node row
    __shared__ ushort xs[2 * NPB * KC * 8];
    constexpr int LOHALF = NPB * KC * 8;  // ushort offset of lo plane
    const int tid = threadIdx.x;
    const int lane = tid & 63;
    const int w = tid >> 6;
    const int n0 = blockIdx.x * NPB;

    // ---- stage x -> bf16 hi/lo, swizzled 16B chunks ----
    for (int c = tid; c < NPB * KC; c += 256) {
        int r = c / KC, kc = c % KC;
        const float4* src = (const float4*)(xin + (size_t)(n0 + r) * FIN + kc * 8);
        float4 x0 = src[0], x1 = src[1];
        float xv[8] = {x0.x, x0.y, x0.z, x0.w, x1.x, x1.y, x1.z, x1.w};
        ushort h[8], l[8];
#pragma unroll
        for (int j = 0; j < 8; ++j) {
            h[j] = f32_to_bf16_rne(xv[j]);
            l[j] = f32_to_bf16_rne(xv[j] - bf16_to_f32(h[j]));
        }
        int kcs = kc ^ (r & 7);
        *(uint4*)&xs[(size_t)(r * KC + kcs) * 8] = *(uint4*)h;
        *(uint4*)&xs[LOHALF + (size_t)(r * KC + kcs) * 8] = *(uint4*)l;
    }

    // bias per (matrix, coltile): same value for all 4 C rows of a fragment
    const int ch16 = lane & 15;
    float bqv[4], bkv[4], bvv[4], bsv[4];
#pragma unroll
    for (int ct = 0; ct < 4; ++ct) {
        bqv[ct] = bq[ct * 16 + ch16];
        bkv[ct] = bk[ct * 16 + ch16];
        bvv[ct] = bv[ct * 16 + ch16];
        bsv[ct] = bs[ct * 16 + ch16];
    }
    float4v acc[2][16];
#pragma unroll
    for (int t = 0; t < 16; ++t) {
        int mat = t >> 2, ct = t & 3;
        float b = (mat == 0) ? bqv[ct] : (mat == 1) ? bkv[ct]
                : (mat == 2) ? bvv[ct] : bsv[ct];
        acc[0][t] = (float4v){b, b, b, b};
        acc[1][t] = (float4v){b, b, b, b};
    }
    __syncthreads();

    const int g = lane >> 4;              // k-chunk group 0..3
    for (int ks = 0; ks < KS; ++ks) {
        short8v ah[2], al[2];
#pragma unroll
        for (int mt = 0; mt < 2; ++mt) {
            int r = w * 32 + mt * 16 + (lane & 15);
            int kcs = (ks * 4 + g) ^ (r & 7);
            ah[mt] = *(const short8v*)&xs[(size_t)(r * KC + kcs) * 8];
            al[mt] = *(const short8v*)&xs[LOHALF + (size_t)(r * KC + kcs) * 8];
        }
#pragma unroll
        for (int t = 0; t < 16; ++t) {
            int mat = t >> 2, ct = t & 3;
            size_t fo = (((size_t)mat * KS * 4) + ks * 4 + ct) * 64 + lane;
            short8v bh = *(const short8v*)&wf_hi[fo * 8];
            short8v bl = *(const short8v*)&wf_lo[fo * 8];
            acc[0][t] = __builtin_amdgcn_mfma_f32_16x16x32_bf16(ah[0], bh, acc[0][t], 0, 0, 0);
            acc[1][t] = __builtin_amdgcn_mfma_f32_16x16x32_bf16(ah[1], bh, acc[1][t], 0, 0, 0);
            acc[0][t] = __builtin_amdgcn_mfma_f32_16x16x32_bf16(al[0], bh, acc[0][t], 0, 0, 0);
            acc[1][t] = __builtin_amdgcn_mfma_f32_16x16x32_bf16(al[1], bh, acc[1][t], 0, 0, 0);
            acc[0][t] = __builtin_amdgcn_mfma_f32_16x16x32_bf16(ah[0], bl, acc[0][t], 0, 0, 0);
            acc[1][t] = __builtin_amdgcn_mfma_f32_16x16x32_bf16(ah[1], bl, acc[1][t], 0, 0, 0);
        }
    }

    // ---- epilogue: C row=(lane>>4)*4+reg, col=lane&15 ----
    const int rloc = (lane >> 4) * 4;
#pragma unroll
    for (int mt = 0; mt < 2; ++mt) {
        int nbase = n0 + w * 32 + mt * 16 + rloc;
#pragma unroll
        for (int t = 0; t < 16; ++t) {
            int mat = t >> 2;
            int ch = (t & 3) * 16 + ch16;
#pragma unroll
            for (int r2 = 0; r2 < 4; ++r2) {
                int n = nbase + r2;
                float v = acc[mt][t][r2];
                if (mat == 0)      q[(size_t)n * HC + ch] = v;
                else if (mat == 1) kv[(size_t)n * 128 + ch] = v;
                else if (mat == 2) kv[(size_t)n * 128 + 64 + ch] = v;
                else               hout[(size_t)n * HC + ch] = v;
            }
        }
    }
}

// ---------------------------------------------------------------------------
// DPP-based 16-lane sum (broadcast). VALU-only, ~10cy vs ~100cy shfl chain.
// ---------------------------------------------------------------------------
__device__ __forceinline__ float dpp_sum16(float x) {
    int t;
    t = __builtin_amdgcn_update_dpp(0, __float_as_int(x), 0xB1, 0xF, 0xF, true);
    x += __int_as_float(t);
    t = __builtin_amdgcn_update_dpp(0, __float_as_int(x), 0x4E, 0xF, 0xF, true);
    x += __int_as_float(t);
    t = __builtin_amdgcn_update_dpp(0, __float_as_int(x), 0x141, 0xF, 0xF, true);
    x += __int_as_float(t);
    t = __builtin_amdgcn_update_dpp(0, __float_as_int(x), 0x140, 0xF, 0xF, true);
    x += __int_as_float(t);
    return x;
}

// ---------------------------------------------------------------------------
// Per-destination-node aggregation with in-register online softmax.
// (unchanged from r10: pairwise updates, readlane broadcast, 1-pair-ahead
// prefetch, DPP head reduce)
// ---------------------------------------------------------------------------
template <int RELU>
__global__ __launch_bounds__(256) void aggregate(
    const float* __restrict__ q, const float* __restrict__ kv,
    const float* __restrict__ ea,
    const float* __restrict__ We, const float* __restrict__ be,
    const int* __restrict__ cnt,
    const int2* __restrict__ bucket, float* __restrict__ hout) {
    const int wave = threadIdx.x >> 6;
    const int c = threadIdx.x & 63;
    const int n = blockIdx.x * 4 + wave;

    const float qc = q[n * HC + c] * 0.25f;
    int deg = cnt[n];
    if (deg > BUCKET_CAP) deg = BUCKET_CAP;

    int myeid = 0, mysrc = 0;
    if (c < deg) {
        int2 b = bucket[n * BUCKET_CAP + c];
        myeid = b.x;
        mysrc = b.y;
    }

    const float bec = be[c];
    float wec[8];
#pragma unroll
    for (int f = 0; f < 8; ++f) wec[f] = We[f * HC + c];

    float m = -INFINITY, d = 0.f, o = 0.f;

    float4 eA0, eA1, eB0, eB1, nA0, nA1, nB0, nB1;
    float kA, vA, kB, vB, nkA, nvA, nkB, nvB;

#define LOAD_EDGE(idx, E0, E1, KC, VC)                                   \
    {                                                                    \
        int eid_ = __builtin_amdgcn_readlane(myeid, (idx));              \
        int s_   = __builtin_amdgcn_readlane(mysrc, (idx));              \
        E0 = *(const float4*)(ea + (size_t)eid_ * 8);                    \
        E1 = *(const float4*)(ea + (size_t)eid_ * 8 + 4);                \
        KC = kv[(size_t)s_ * 128 + c];                                   \
        VC = kv[(size_t)s_ * 128 + 64 + c];                              \
    }

#define EDGE_PROJ(E0, E1, EC)                                            \
    float EC = bec;                                                      \
    EC = fmaf(E0.x, wec[0], EC); EC = fmaf(E0.y, wec[1], EC);            \
    EC = fmaf(E0.z, wec[2], EC); EC = fmaf(E0.w, wec[3], EC);            \
    EC = fmaf(E1.x, wec[4], EC); EC = fmaf(E1.y, wec[5], EC);            \
    EC = fmaf(E1.z, wec[6], EC); EC = fmaf(E1.w, wec[7], EC);

    const int npairs = deg >> 1;

    if (deg >= 2) {
        LOAD_EDGE(0, eA0, eA1, kA, vA);
        LOAD_EDGE(1, eB0, eB1, kB, vB);
    } else if (deg == 1) {
        LOAD_EDGE(0, eA0, eA1, kA, vA);
    }

    for (int p = 0; p < npairs; ++p) {
        int base = (p + 1) * 2;
        if (base + 1 < deg) {
            LOAD_EDGE(base, nA0, nA1, nkA, nvA);
            LOAD_EDGE(base + 1, nB0, nB1, nkB, nvB);
        } else if (base < deg) {
            LOAD_EDGE(base, nA0, nA1, nkA, nvA);
        }

        EDGE_PROJ(eA0, eA1, ecA);
        EDGE_PROJ(eB0, eB1, ecB);

        float pA = dpp_sum16(qc * (kA + ecA));
        float pB = dpp_sum16(qc * (kB + ecB));

        float newm = fmaxf(m, fmaxf(pA, pB));
        float scale = __expf(m - newm);
        float wA = __expf(pA - newm);
        float wB = __expf(pB - newm);
        d = d * scale + wA + wB;
        o = o * scale + (vA + ecA) * wA + (vB + ecB) * wB;
        m = newm;

        eA0 = nA0; eA1 = nA1; kA = nkA; vA = nvA;
        eB0 = nB0; eB1 = nB1; kB = nkB; vB = nvB;
    }

    if (deg & 1) {
        EDGE_PROJ(eA0, eA1, ecA);
        float pA = dpp_sum16(qc * (kA + ecA));
        float newm = fmaxf(m, pA);
        float scale = __expf(m - newm);
        float wA = __expf(pA - newm);
        d = d * scale + wA;
        o = o * scale + (vA + ecA) * wA;
    }

#undef LOAD_EDGE
#undef EDGE_PROJ

    float msg = (deg > 0) ? (o / d) : 0.f;
    float val = hout[n * HC + c] + msg;
    if (RELU) val = fmaxf(val, 0.f);
    hout[n * HC + c] = val;
}

// ---------------------------------------------------------------------------
// Mean pool (binary-search ranges over sorted batch).
// ---------------------------------------------------------------------------
__device__ __forceinline__ int lower_bound(const int* __restrict__ b, int val) {
    int lo = 0, hi = N_NODES;
    while (lo < hi) {
        int mid = (lo + hi) >> 1;
        if (b[mid] < val) lo = mid + 1; else hi = mid;
    }
    return lo;
}

__global__ __launch_bounds__(256) void pool_graph(const float* __restrict__ h,
                                                  const int* __restrict__ batch,
                                                  float* __restrict__ out) {
    const int g = blockIdx.x * 4 + (threadIdx.x >> 6);
    const int c = threadIdx.x & 63;
    const int s = lower_bound(batch, g);
    const int e = lower_bound(batch, g + 1);

    float a0 = 0.f, a1 = 0.f, a2 = 0.f, a3 = 0.f;
    int i = s;
    for (; i + 4 <= e; i += 4) {
        a0 += h[(size_t)i * HC + c];
        a1 += h[(size_t)(i + 1) * HC + c];
        a2 += h[(size_t)(i + 2) * HC + c];
        a3 += h[(size_t)(i + 3) * HC + c];
    }
    for (; i < e; ++i) a0 += h[(size_t)i * HC + c];
    float acc = (a0 + a1) + (a2 + a3);
    out[g * HC + c] = acc / fmaxf((float)(e - s), 1.f);
}

// ---------------------------------------------------------------------------
extern "C" void kernel_launch(void* const* d_in, const int* in_sizes, int n_in,
                              void* d_out, int out_size, void* d_ws, size_t ws_size,
                              hipStream_t stream) {
    const float* x     = (const float*)d_in[0];
    const float* ea    = (const float*)d_in[1];
    const int*   ei    = (const int*)d_in[2];
    const int*   batch = (const int*)d_in[3];
    const float* Wq1 = (const float*)d_in[4];
    const float* Wk1 = (const float*)d_in[5];
    const float* Wv1 = (const float*)d_in[6];
    const float* We1 = (const float*)d_in[7];
    const float* Ws1 = (const float*)d_in[8];
    const float* Wq2 = (const float*)d_in[9];
    const float* Wk2 = (const float*)d_in[10];
    const float* Wv2 = (const float*)d_in[11];
    const float* We2 = (const float*)d_in[12];
    const float* Ws2 = (const float*)d_in[13];
    const float* bq1 = (const float*)d_in[14];
    const float* bk1 = (const float*)d_in[15];
    const float* bv1 = (const float*)d_in[16];
    const float* be1 = (const float*)d_in[17];
    const float* bs1 = (const float*)d_in[18];
    const float* bq2 = (const float*)d_in[19];
    const float* bk2 = (const float*)d_in[20];
    const float* bv2 = (const float*)d_in[21];
    const float* be2 = (const float*)d_in[22];
    const float* bs2 = (const float*)d_in[23];
    float* out = (float*)d_out;

    char* ws = (char*)d_ws;
    size_t off = 0;
    auto alloc = [&](size_t bytes) -> void* {
        void* p = ws + off;
        off += (bytes + 255) & ~(size_t)255;
        return p;
    };
    int*    cnt    = (int*)alloc((size_t)N_NODES * 4);
    int2*   bucket = (int2*)alloc((size_t)N_NODES * BUCKET_CAP * 8);
    float*  q      = (float*)alloc((size_t)N_NODES * HC * 4);
    float*  kv     = (float*)alloc((size_t)N_NODES * 128 * 4);
    float*  h1     = (float*)alloc((size_t)N_NODES * HC * 4);
    float*  h2     = (float*)alloc((size_t)N_NODES * HC * 4);
    ushort* wf1_hi = (ushort*)alloc((size_t)4 * 1024 * 8 * 2);
    ushort* wf1_lo = (ushort*)alloc((size_t)4 * 1024 * 8 * 2);
    ushort* wf2_hi = (ushort*)alloc((size_t)4 * 512 * 8 * 2);
    ushort* wf2_lo = (ushort*)alloc((size_t)4 * 512 * 8 * 2);

    hipMemsetAsync(cnt, 0, (size_t)N_NODES * 4, stream);
    build_buckets<<<N_EDGES / 256, 256, 0, stream>>>(ei, cnt, bucket);
    pack_weights<<<24, 256, 0, stream>>>(Wq1, Wk1, Wv1, Ws1, Wq2, Wk2, Wv2, Ws2,
                                         wf1_hi, wf1_lo, wf2_hi, wf2_lo);

    // ---- layer 1 ----
    node_gemm_mfma<IN_CH><<<N_NODES / 128, 256, 0, stream>>>(
        x, wf1_hi, wf1_lo, bq1, bk1, bv1, bs1, q, kv, h1);
    aggregate<1><<<N_NODES / 4, 256, 0, stream>>>(
        q, kv, ea, We1, be1, cnt, bucket, h1);

    // ---- layer 2 ----
    node_gemm_mfma<HC><<<N_NODES / 128, 256, 0, stream>>>(
        h1, wf2_hi, wf2_lo, bq2, bk2, bv2, bs2, q, kv, h2);
    aggregate<0><<<N_NODES / 4, 256, 0, stream>>>(
        q, kv, ea, We2, be2, cnt, bucket, h2);

    // ---- mean pool ----
    pool_graph<<<N_GRAPHS / 4, 256, 0, stream>>>(h2, batch, out);
}